// Round 1
// 159.668 us; speedup vs baseline: 1.0984x; 1.0984x over previous
//
#include <hip/hip_runtime.h>
#include <cstdint>
#include <cstddef>

typedef unsigned short u16;
typedef __attribute__((ext_vector_type(8))) __bf16 bf16x8;
typedef __attribute__((ext_vector_type(4))) float f32x4;

__device__ __forceinline__ u16 f2bf(float f) {
  unsigned u = __float_as_uint(f);
  u += 0x7FFFu + ((u >> 16) & 1u);   // round-to-nearest-even
  return (u16)(u >> 16);
}

__device__ __forceinline__ float bf2f(u16 h) {
  return __uint_as_float(((unsigned)h) << 16);
}

__device__ __forceinline__ void async16(u16* lds, const u16* g) {
  __builtin_amdgcn_global_load_lds(
      (const __attribute__((address_space(1))) unsigned int*)g,
      (__attribute__((address_space(3))) unsigned int*)lds, 16, 0, 0);
}

// ---------------- prep: x->bf16 (blocks 0..3071) + TT pre-pass (blocks 3072..4295) ----
__global__ __launch_bounds__(256)
void prep(const float4* __restrict__ x4, ushort4* __restrict__ xb4,
          const float* __restrict__ gA1, const float* __restrict__ gB1,
          const float* __restrict__ gC1, const float* __restrict__ gD1,
          const float* __restrict__ gA2, const float* __restrict__ gB2,
          const float* __restrict__ gC2, const float* __restrict__ gD2,
          float* __restrict__ B12_1, float* __restrict__ B12_2,
          float* __restrict__ C1, float* __restrict__ C2) {
  const int b = blockIdx.x;
  const int tid = threadIdx.x;
  if (b < 3072) {
    int i = b * 256 + tid;
    float4 v = x4[i];
    ushort4 o;
    o.x = f2bf(v.x); o.y = f2bf(v.y); o.z = f2bf(v.z); o.w = f2bf(v.w);
    xb4[i] = o;
    return;
  }
  int idx = (b - 3072) * 256 + tid;
  if (idx < 9216) {
    int e = idx;
    int r2 = e % 24; int t = e / 24;
    int fo12 = t % 24, fi12 = t / 24;
    int i2 = fi12 % 4, i1 = fi12 / 4;
    int o2 = fo12 % 6, o1 = fo12 / 6;
    float s = 0.f;
#pragma unroll
    for (int r1 = 0; r1 < 12; ++r1)
      s += gA1[(i1 * 4 + o1) * 12 + r1] * gB1[((r1 * 4 + i2) * 6 + o2) * 24 + r2];
    B12_1[e] = s;
  } else if (idx < 18432) {
    int e = idx - 9216;
    int r2 = e % 24; int t = e / 24;
    int fo12 = t % 16, fi12 = t / 16;
    int i2 = fi12 % 6, i1 = fi12 / 6;
    int o2 = fo12 % 4, o1 = fo12 / 4;
    float s = 0.f;
#pragma unroll
    for (int r1 = 0; r1 < 12; ++r1)
      s += gA2[(i1 * 4 + o1) * 12 + r1] * gB2[((r1 * 6 + i2) * 4 + o2) * 24 + r2];
    B12_2[e] = s;
  } else if (idx < 165888) {
    int e = idx - 18432;
    int fi34 = e % 48; int t = e / 48;
    int fo34 = t % 128;
    int i3 = fi34 / 8, i4 = fi34 % 8;
    int o3 = fo34 / 16, o4 = fo34 % 16;
    int r2 = t / 128;
    float s = 0.f;
#pragma unroll
    for (int r3 = 0; r3 < 12; ++r3)
      s += gC1[((r2 * 6 + i3) * 8 + o3) * 12 + r3] * gD1[(r3 * 8 + i4) * 16 + o4];
    C1[e] = s;
  } else {
    int e = idx - 165888;
    int fi34 = e % 128; int t = e / 128;
    int fo34 = t % 48;
    int i3 = fi34 / 16, i4 = fi34 % 16;
    int o3 = fo34 / 8, o4 = fo34 % 8;
    int r2 = t / 48;
    float s = 0.f;
#pragma unroll
    for (int r3 = 0; r3 < 12; ++r3)
      s += gC2[((r2 * 8 + i3) * 6 + o3) * 12 + r3] * gD2[(r3 * 16 + i4) * 8 + o4];
    C2[e] = s;
  }
}

// ---------------- TT expand (device body): Wt[out][in] = sum_r2 B12*C34t ----------------
template <int FI12, int I34, int O12, int O34, int OG>
__device__ __forceinline__
void tt_expand_body(const float* __restrict__ B12, const float* __restrict__ C34t,
                    u16* __restrict__ Wt, int bx, int by, int tid, float* sB) {
  constexpr int R2 = 24;
  constexpr int Kin = FI12 * I34;
  constexpr int IC = Kin / 8;
  constexpr int I34C = I34 / 8;
  for (int e = tid; e < FI12 * OG * R2; e += 256) {
    int r2 = e % R2; int t = e / R2;
    int f = t % OG; int fi12 = t / OG;
    sB[(fi12 * OG + f) * 25 + r2] = B12[(fi12 * O12 + by * OG + f) * R2 + r2];
  }
  __syncthreads();
  const int t = bx * 256 + tid;
  const int fo34 = t / IC;
  const int ic = t % IC;
  const int fi12 = ic / I34C;
  const int fi34 = (ic % I34C) * 8;

  float acc[OG][8];
#pragma unroll
  for (int f = 0; f < OG; ++f)
#pragma unroll
    for (int k = 0; k < 8; ++k) acc[f][k] = 0.f;

  for (int r2 = 0; r2 < R2; ++r2) {
    const float4* cp = (const float4*)(C34t + ((size_t)(r2 * O34 + fo34) * I34 + fi34));
    float4 c0 = cp[0], c1 = cp[1];
    float c[8] = {c0.x, c0.y, c0.z, c0.w, c1.x, c1.y, c1.z, c1.w};
#pragma unroll
    for (int f = 0; f < OG; ++f) {
      float bb = sB[(fi12 * OG + f) * 25 + r2];
#pragma unroll
      for (int k = 0; k < 8; ++k) acc[f][k] += bb * c[k];
    }
  }
#pragma unroll
  for (int f = 0; f < OG; ++f) {
    int out = (by * OG + f) * O34 + fo34;
    u16 v[8];
#pragma unroll
    for (int k = 0; k < 8; ++k) v[k] = f2bf(acc[f][k]);
    *(uint4*)(Wt + (size_t)out * Kin + fi12 * I34 + fi34) = *(const uint4*)v;
  }
}

// Merged: blocks 0..287 -> layer1 (48x6); blocks 288..575 -> layer2 (72x4)
__global__ __launch_bounds__(256)
void tt_expand2(const float* __restrict__ B12_1, const float* __restrict__ C1, u16* __restrict__ W1t,
                const float* __restrict__ B12_2, const float* __restrict__ C2, u16* __restrict__ W2t) {
  __shared__ float sB[24 * 4 * 25];
  const int b = blockIdx.x;
  const int tid = threadIdx.x;
  if (b < 288) {
    tt_expand_body<16, 48, 24, 128, 4>(B12_1, C1, W1t, b % 48, b / 48, tid, sB);
  } else {
    int bb = b - 288;
    tt_expand_body<24, 128, 16, 48, 4>(B12_2, C2, W2t, bb % 72, bb / 72, tid, sB);
  }
}

// out = bias2 + sum of nz bf16 partials; 8 elems/thread, 16B partial loads
__global__ void reduceN8(const uint4* __restrict__ P, const float* __restrict__ bias,
                         float4* __restrict__ out4, int n8, int zstride8, int nz) {
  int i = blockIdx.x * 256 + threadIdx.x;
  if (i >= n8) return;
  int b0 = (i % 96) * 8;
  float a[8];
#pragma unroll
  for (int k = 0; k < 8; ++k) a[k] = bias[b0 + k];
  for (int s = 0; s < nz; ++s) {
    uint4 u = P[i + s * zstride8];
    const u16* up = (const u16*)&u;
#pragma unroll
    for (int k = 0; k < 8; ++k) a[k] += bf2f(up[k]);
  }
  out4[i * 2]     = (float4){a[0], a[1], a[2], a[3]};
  out4[i * 2 + 1] = (float4){a[4], a[5], a[6], a[7]};
}

// ---------------- bf16 MFMA GEMM, C = A(MxK) * Bt(NxK)^T ----------------
// R14: L2-RECTANGLE XCD mapping. Old swizzle gave each XCD a 3-wide bn stripe
// x ALL 32 bm -> full 6.3MB A cycled through the 4MB per-XCD L2 every pass;
// A-reads (151MB/GEMM) spilled to L3 and the ~500-700cy L3 latency sat inside
// the per-iter vmcnt(0)-drain critical path (grid-limited 3 lockstep blocks/CU
// can't hide it). New mapping gives each XCD a RECTANGLE whose A+B slices fit
// its 4MB L2:
//   MAP=1 (GEMM1, 32bm x 24bn):      8bm x 12bn  -> 1.57 + 2.36 = 3.9 MB
//   MAP=2 (GEMM2, 32bm x 6bn x 4bz): 16bm x 6bn x 1bz -> 3.1 + 1.18 = 4.3 MB
// Mapping is locality-only (any block->tile bijection stays correct).
// R14b: erff epilogue (64/thread, ~40 instr each, serial tail with no tail
// blocks to overlap) -> tanh-form GELU via v_exp_f32+v_rcp_f32 (~7 ops,
// max dev from exact-erf ~5e-4 < bf16 quantum of h).
template <bool GELU, int MAP>
__global__ __launch_bounds__(256, 3)
void gemm_bt(const u16* __restrict__ A, const u16* __restrict__ Bt,
             const float* __restrict__ bias, u16* __restrict__ Out,
             int N, int K, int klen, size_t zstride) {
  const int flat = blockIdx.x;
  const int xcd = flat & 7;        // HW round-robins blockIdx over 8 XCDs
  const int local = flat >> 3;     // 0..95
  int bm, bn, bz;
  if (MAP == 1) {                  // 8 XCD rects of 8bm x 12bn
    bm = (xcd >> 1) * 8 + (local & 7);
    bn = (xcd & 1) * 12 + (local >> 3);
    bz = 0;
  } else {                         // 8 XCD groups of 16bm x 6bn x 1bz
    bm = (xcd & 1) * 16 + (local & 15);
    bn = local >> 4;
    bz = xcd >> 1;
  }

  __shared__ __align__(16) u16 As[2][128 * 32];
  __shared__ __align__(16) u16 Bs[2][128 * 32];
  const int tid = threadIdx.x;
  const int wave = tid >> 6, lane = tid & 63;
  const int wm = (wave & 1) * 64, wn = (wave >> 1) * 64;
  const int lr = lane & 15, lq = lane >> 4;

  const int srow = tid >> 2;
  const int scol = (tid & 3) * 8;
  const u16* Ag = A + (size_t)(bm * 128 + srow) * K + scol;
  const u16* Bg = Bt + (size_t)(bn * 128 + srow) * K + scol;
  u16* AsW = &As[0][0] + tid * 8;
  u16* BsW = &Bs[0][0] + tid * 8;

  f32x4 acc[4][4];
#pragma unroll
  for (int i = 0; i < 4; i++)
#pragma unroll
    for (int j = 0; j < 4; j++) acc[i][j] = (f32x4){0.f, 0.f, 0.f, 0.f};

  const int kbeg = bz * klen;
  const int nIter = klen >> 5;   // even

  auto stage = [&](int buf, int k0) {
    async16(AsW + buf * 4096,        Ag + k0);
    async16(AsW + buf * 4096 + 2048, Ag + k0 + (size_t)64 * K);
    async16(BsW + buf * 4096,        Bg + k0);
    async16(BsW + buf * 4096 + 2048, Bg + k0 + (size_t)64 * K);
  };
  auto compute = [&](int buf) {
    bf16x8 af[4], bfr[4];
#pragma unroll
    for (int i = 0; i < 4; i++)
      af[i] = *(const bf16x8*)(&As[buf][0] + (wm + i * 16 + lr) * 32 + lq * 8);
#pragma unroll
    for (int j = 0; j < 4; j++)
      bfr[j] = *(const bf16x8*)(&Bs[buf][0] + (wn + j * 16 + lr) * 32 + lq * 8);
#pragma unroll
    for (int i = 0; i < 4; i++)
#pragma unroll
      for (int j = 0; j < 4; j++)
        acc[i][j] = __builtin_amdgcn_mfma_f32_16x16x32_bf16(af[i], bfr[j], acc[i][j], 0, 0, 0);
  };

  stage(0, kbeg);                      // prologue
  for (int it = 0; it < nIter; it += 2) {
    __syncthreads();                   // buf0 staged; buf1 readers done
    if (it + 1 < nIter) stage(1, kbeg + (it + 1) * 32);
    compute(0);
    __syncthreads();                   // buf1 staged; buf0 readers done
    if (it + 2 < nIter) stage(0, kbeg + (it + 2) * 32);
    compute(1);
  }

  u16* Op = Out + (size_t)bz * zstride;
  // C/D layout: col = lane&15, row = (lane>>4)*4 + reg  [verified m89/m91]
  const int r0 = bm * 128 + wm + lq * 4;
  const int c0 = bn * 128 + wn + lr;
  float bv[4];
  if (GELU) {
#pragma unroll
    for (int j = 0; j < 4; j++) bv[j] = bias[c0 + j * 16];
  }
#pragma unroll
  for (int i = 0; i < 4; i++) {
#pragma unroll
    for (int r = 0; r < 4; r++) {
      const size_t rowoff = (size_t)(r0 + i * 16 + r) * N;
#pragma unroll
      for (int j = 0; j < 4; j++) {
        float v = acc[i][j][r];
        if (GELU) {
          v += bv[j];
          // tanh-form GELU: x*(1 - 1/(1+exp(2*(0.79788456x + 0.035677408x^3))))
          float inner = v * fmaf(v * v, 0.0356774081f, 0.7978845608f);
          float e = __builtin_amdgcn_exp2f(2.8853900818f * inner);
          float r1 = __builtin_amdgcn_rcpf(1.0f + e);
          v = v - v * r1;             // e=inf -> r1=0 -> v; e=0 -> r1=1 -> 0
        }
        Op[rowoff + c0 + j * 16] = f2bf(v);
      }
    }
  }
}

extern "C" void kernel_launch(void* const* d_in, const int* in_sizes, int n_in,
                              void* d_out, int out_size, void* d_ws, size_t ws_size,
                              hipStream_t stream) {
  const float* x   = (const float*)d_in[0];
  const float* g1a = (const float*)d_in[1];
  const float* g1b = (const float*)d_in[2];
  const float* g1c = (const float*)d_in[3];
  const float* g1d = (const float*)d_in[4];
  const float* b1  = (const float*)d_in[5];
  const float* g2a = (const float*)d_in[6];
  const float* g2b = (const float*)d_in[7];
  const float* g2c = (const float*)d_in[8];
  const float* g2d = (const float*)d_in[9];
  const float* b2  = (const float*)d_in[10];
  float* out = (float*)d_out;

  char* ws = (char*)d_ws;
  u16* xb   = (u16*)(ws + 0);          // 4096x768 bf16   = 6291456 B
  u16* W1t  = (u16*)(ws + 6291456);    // 3072x768 bf16   = 4718592 B
  u16* W2t  = (u16*)(ws + 11010048);   // 768x3072 bf16   = 4718592 B
  u16* h    = (u16*)(ws + 15728640);   // 4096x3072 bf16  = 25165824 B
  u16* Part = (u16*)(ws + 40894464);   // 4 x 4096x768 bf16
  // TT scratch ALIASES Part (dead before gemm2 writes Part; stream-ordered)
  float* B12_1 = (float*)(ws + 40894464);            // 9216 f32
  float* B12_2 = (float*)(ws + 40894464 + 36864);    // 9216 f32
  float* C1    = (float*)(ws + 40894464 + 73728);    // 147456 f32
  float* C2    = (float*)(ws + 40894464 + 663552);   // 147456 f32

  // x->bf16 (blocks 0..3071) + TT pre-pass (blocks 3072..4295)
  prep<<<4296, 256, 0, stream>>>((const float4*)x, (ushort4*)xb,
                                 g1a, g1b, g1c, g1d, g2a, g2b, g2c, g2d,
                                 B12_1, B12_2, C1, C2);

  // merged expand: layer1 (blocks 0..287) + layer2 (blocks 288..575)
  tt_expand2<<<576, 256, 0, stream>>>(B12_1, C1, W1t, B12_2, C2, W2t);

  // GEMM1: h = gelu(x @ W1 + b1)  (4096x3072, K=768); per-XCD 8bm x 12bn rect
  gemm_bt<true, 1><<<768, 256, 0, stream>>>(xb, W1t, b1, h, 3072, 768, 768, 0);
  // GEMM2: bf16 partials, K=3072 split 4 ways; per-XCD 16bm x 6bn x 1bz rect
  gemm_bt<false, 2><<<768, 256, 0, stream>>>(h, W2t, nullptr, Part, 768, 3072, 768, 3145728);
  // out = b2 + sum(partials)
  reduceN8<<<1536, 256, 0, stream>>>((const uint4*)Part, b2,
                                     (float4*)out, 393216, 393216, 4);
}